// Round 18
// baseline (339.389 us; speedup 1.0000x reference)
//
#include <hip/hip_runtime.h>
#include <hip/hip_bf16.h>
#include <stdint.h>

using bf16 = __hip_bfloat16;
using mfrag = __attribute__((ext_vector_type(8))) __bf16;   // 8 bf16 = 4 VGPRs
using f32x4 = __attribute__((ext_vector_type(4))) float;

#define TOKENS 4096
#define HID    2048
#define VD     3072
#define NH     6
#define HD     512
#define NPAIR  256
#define N1     9216     /* q_even(1536) | k_even(1536) | v(3072) | g(3072) */
#define NC     128
#define CHUNK  16

#define NPREP1 ((N1 / 32) * (HID / 32))   /* 18432 */
#define NPREP2 ((HID / 32) * (VD / 32))   /*  6144 */

__device__ __forceinline__ void gld_lds16(const bf16* g, bf16* l) {
    __builtin_amdgcn_global_load_lds((const __attribute__((address_space(1))) void*)g,
                                     (__attribute__((address_space(3))) void*)l, 16, 0, 0);
}

#define VMWAIT(n) asm volatile("s_waitcnt vmcnt(" #n ")" ::: "memory")
#define SCHED0    __builtin_amdgcn_sched_barrier(0)
#define SBAR      __builtin_amdgcn_s_barrier()

// ================================================================ BK=32 2-phase GEMM body (2 blocks/CU)
// BM=256 x BN=128, BK=32, 512 thr = 8 waves (wm=wave>>1 in 0..3 row-64s, wn=wave&1 col-64s).
// LDS 48 KB (2 x 24 KB) -> two co-resident blocks per CU: cross-block MFMA/LDS overlap.
// Rows are 64 B -> frag reads are contiguous 1 KB per wave: conflict-free, NO swizzle.
// Per K-tile 3 stage loads {B, Ap0, Ap1}; waits {A:1, B:2}, last {1,0} (FIFO-traced).
// Ap0/Ap1 = phase-matched A bands: rows wm*64+[0,32) / +[32,64) for all wm.
__device__ __forceinline__ void gemm_body32(int bid, const bf16* __restrict__ A,
                                            const bf16* __restrict__ Bt,
                                            void* __restrict__ Cv,
                                            int N, int K, int obf,
                                            int n0, int nbn, char* smem) {
    constexpr int SLOT = 24576;            // A 16 KB + B 8 KB
    const int tid  = threadIdx.x;
    const int wave = tid >> 6;
    const int lane = tid & 63;
    const int lrow = lane & 15;
    const int lk   = lane >> 4;            // k-chunk 0..3 (k = lk*8)
    const int wm   = wave >> 1;
    const int wn   = wave & 1;

    // supertile-per-XCD mapping (bijective for nbn=64 and nbn=8; grid = 8*4*(nbn/2))
    const int xcd = bid & 7;
    const int kk2 = bid >> 3;
    const int rn  = nbn >> 1;
    const int jj  = kk2 & 31;
    const int bm  = ((((xcd >> 1) << 2) + (jj & 3)) << 8);
    const int bn  = ((xcd & 1) * rn + (kk2 >> 5) * 8 + (jj >> 2)) * 128;

    const int NT = K >> 5;

    auto ST_B32 = [&](int t) {             // B: 128 rows x 32 (8 KB), 1 load/thread
        char* sb = smem + (size_t)(t & 1) * SLOT + 16384;
        const int ko = t << 5;
        const int r = tid >> 2;
        const int c = tid & 3;
        gld_lds16(Bt + (size_t)(bn + r) * K + ko + c * 8,
                  (bf16*)(sb + (size_t)tid * 16));
    };
    auto ST_Ap = [&](int half, int t) {    // A band: rows wm*64+[half*32, half*32+32) (8 KB)
        char* sb = smem + (size_t)(t & 1) * SLOT;
        const int ko = t << 5;
        const int r = (tid >> 7) * 64 + ((tid >> 2) & 31) + half * 32;
        const int c = tid & 3;
        gld_lds16(A + (size_t)(bm + r) * K + ko + c * 8,
                  (bf16*)(sb + (size_t)r * 64 + c * 16));   // wave-uniform base + lane*16
    };

    auto rdA32 = [&](const char* rb, int mf) -> mfrag {
        const int r = wm * 64 + mf * 16 + lrow;
        return *(const mfrag*)(rb + (size_t)r * 64 + lk * 16);
    };
    auto rdB32 = [&](const char* rb, int nf) -> mfrag {
        const int r = wn * 64 + nf * 16 + lrow;
        return *(const mfrag*)(rb + 16384 + (size_t)r * 64 + lk * 16);
    };

    f32x4 acc[4][4];
#pragma unroll
    for (int m = 0; m < 4; ++m)
#pragma unroll
        for (int n = 0; n < 4; ++n) acc[m][n] = f32x4{0.f, 0.f, 0.f, 0.f};

    // prologue: tile 0 in FIFO order B, Ap0, Ap1
    ST_B32(0); ST_Ap(0, 0); ST_Ap(1, 0);

    for (int kt = 0; kt < NT; ++kt) {
        const char* rb = smem + (size_t)(kt & 1) * SLOT;
        const bool last = (kt == NT - 1);
        mfrag bfr[4];
        mfrag afA[2], afB[2];

        // ---- phase A: wait publishes B(t), Ap0(t) [issued 2 phases earlier]
        VMWAIT(1);
        SCHED0; SBAR;
#pragma unroll
        for (int nf = 0; nf < 4; ++nf) bfr[nf] = rdB32(rb, nf);
        afA[0] = rdA32(rb, 0);
        afA[1] = rdA32(rb, 1);
        if (!last) { ST_B32(kt + 1); ST_Ap(0, kt + 1); }
        SCHED0;
        __builtin_amdgcn_s_setprio(1);
#pragma unroll
        for (int i = 0; i < 2; ++i)
#pragma unroll
            for (int nf = 0; nf < 4; ++nf)
                acc[i][nf] = __builtin_amdgcn_mfma_f32_16x16x32_bf16(afA[i], bfr[nf], acc[i][nf], 0, 0, 0);
        __builtin_amdgcn_s_setprio(0);

        // ---- phase B: wait publishes Ap1(t) [issued 2 phases earlier]
        if (last) { VMWAIT(0); } else { VMWAIT(2); }
        SCHED0; SBAR;
        afB[0] = rdA32(rb, 2);
        afB[1] = rdA32(rb, 3);
        if (!last) ST_Ap(1, kt + 1);
        SCHED0;
        __builtin_amdgcn_s_setprio(1);
#pragma unroll
        for (int i = 0; i < 2; ++i)
#pragma unroll
            for (int nf = 0; nf < 4; ++nf)
                acc[2 + i][nf] = __builtin_amdgcn_mfma_f32_16x16x32_bf16(afB[i], bfr[nf], acc[2 + i][nf], 0, 0, 0);
        __builtin_amdgcn_s_setprio(0);
    }

    // epilogue
#pragma unroll
    for (int m = 0; m < 4; ++m)
#pragma unroll
        for (int j2 = 0; j2 < 4; ++j2) {
            const int r = bm + wm * 64 + m * 16 + lk * 4 + j2;
#pragma unroll
            for (int n = 0; n < 4; ++n) {
                const int c = n0 + bn + wn * 64 + n * 16 + lrow;
                if (obf) ((bf16*)Cv)[(size_t)r * N + c] = __float2bfloat16(acc[m][n][j2]);
                else     ((float*)Cv)[(size_t)r * N + c] = acc[m][n][j2];
            }
        }
}

// ---- merged GEMM-1: blocks 0-1023 main (cols 0-8191, nbn=64), 1024-1151 tail (cols 8192+, nbn=8)
__global__ __launch_bounds__(512, 4) void k_gemm1(const bf16* __restrict__ A,
                                                  const bf16* __restrict__ Wt,
                                                  bf16* __restrict__ X) {
    extern __shared__ char smem[];
    if (blockIdx.x < 1024)
        gemm_body32(blockIdx.x, A, Wt, X, N1, HID, 1, 0, 64, smem);
    else
        gemm_body32(blockIdx.x - 1024, A, Wt + (size_t)8192 * HID, X, N1, HID, 1, 8192, 8, smem);
}

// ================================================================ BK=64 2-phase body (r17, kept for GEMM-2)
template<int BN_T>
__device__ __forceinline__ void gemm_body(int bid, const bf16* __restrict__ A,
                                          const bf16* __restrict__ Bt,
                                          void* __restrict__ Cv,
                                          int M, int N, int K, int obf,
                                          int n0, int nbn, char* smem) {
    constexpr int WN   = 2;
    constexpr int WM   = 8 / WN;
    constexpr int MF   = (256 / WM) / 16;
    constexpr int SH   = (MF / 4) * 16;
    constexpr int NHT  = 3;
    constexpr int HT   = 16384;
    constexpr int SLOT = NHT * HT;

    const int tid  = threadIdx.x;
    const int wave = tid >> 6;
    const int lane = tid & 63;
    const int lrow = lane & 15;
    const int lk   = lane >> 4;
    const int wm   = wave / WN;
    const int wn   = wave % WN;

    const int xcd = bid & 7;
    const int kk2 = bid >> 3;
    const int rn  = nbn >> 1;
    const int jj  = kk2 & 31;
    const int bm  = ((((xcd >> 1) << 2) + (jj & 3)) << 8);
    const int bn  = ((xcd & 1) * rn + (kk2 >> 5) * 8 + (jj >> 2)) * BN_T;

    const int NT = K >> 6;

    auto ST_B = [&](int half, int t) {
        char* sb = smem + (size_t)(t & 1) * SLOT + (2 + half) * HT;
        const int ko = t << 6;
#pragma unroll
        for (int i = 0; i < 2; ++i) {
            const int L = i * 512 + tid;
            const int r = L >> 3;
            const int c = (L & 7) ^ (r & 7);
            gld_lds16(Bt + (size_t)(bn + half * 128 + r) * K + ko + c * 8,
                      (bf16*)(sb + (size_t)L * 16));
        }
    };
    auto ST_A = [&](int unit, int t) {
        char* sb = smem + (size_t)(t & 1) * SLOT;
        const int ko = t << 6;
        const int s  = tid / (SH * 8);
        const int W  = tid % (SH * 8);
        const int rl = W >> 3;
        const int c  = W & 7;
        const int r256 = s * (256 / WM) + unit * SH + rl;
        const int cl = c ^ (r256 & 7);
        const int ht = r256 >> 7, lr = r256 & 127;
        gld_lds16(A + (size_t)(bm + r256) * K + ko + cl * 8,
                  (bf16*)(sb + (size_t)ht * HT + (size_t)lr * 128 + c * 16));
    };

    auto rdA = [&](const char* rb, int mf, int kk) -> mfrag {
        const int r  = wm * (MF * 16) + mf * 16 + lrow;
        const int ht = r >> 7, lr = r & 127;
        const int cc = (kk * 4 + lk) ^ (lr & 7);
        return *(const mfrag*)(rb + (size_t)ht * HT + (size_t)lr * 128 + cc * 16);
    };
    auto rdB = [&](const char* rb, int nf, int kk) -> mfrag {
        const int r  = wn * 64 + nf * 16 + lrow;
        const int ht = r >> 7, lr = r & 127;
        const int cc = (kk * 4 + lk) ^ (lr & 7);
        return *(const mfrag*)(rb + (size_t)(2 + ht) * HT + (size_t)lr * 128 + cc * 16);
    };

    f32x4 acc[MF][4];
#pragma unroll
    for (int m = 0; m < MF; ++m)
#pragma unroll
        for (int n = 0; n < 4; ++n) acc[m][n] = f32x4{0.f, 0.f, 0.f, 0.f};

    ST_B(0, 0);
    ST_A(0, 0); ST_A(1, 0); ST_A(2, 0); ST_A(3, 0);

    for (int kt = 0; kt < NT; ++kt) {
        const char* rb = smem + (size_t)(kt & 1) * SLOT;
        const bool last = (kt == NT - 1);
        mfrag bfr[4][2];
        mfrag afA[2][2], afB[2][2];

        // phase A
        VMWAIT(2);
        SCHED0; SBAR;
#pragma unroll
        for (int nf = 0; nf < 4; ++nf)
#pragma unroll
            for (int kx = 0; kx < 2; ++kx) bfr[nf][kx] = rdB(rb, nf, kx);
#pragma unroll
        for (int i = 0; i < 2; ++i)
#pragma unroll
            for (int kx = 0; kx < 2; ++kx) afA[i][kx] = rdA(rb, i, kx);
        if (!last) { ST_B(0, kt + 1); ST_A(0, kt + 1); ST_A(1, kt + 1); }
        SCHED0;
        __builtin_amdgcn_s_setprio(1);
#pragma unroll
        for (int i = 0; i < 2; ++i)
#pragma unroll
            for (int nf = 0; nf < 4; ++nf) {
                acc[i][nf] = __builtin_amdgcn_mfma_f32_16x16x32_bf16(afA[i][0], bfr[nf][0], acc[i][nf], 0, 0, 0);
                acc[i][nf] = __builtin_amdgcn_mfma_f32_16x16x32_bf16(afA[i][1], bfr[nf][1], acc[i][nf], 0, 0, 0);
            }
        __builtin_amdgcn_s_setprio(0);

        // phase B
        if (last) { VMWAIT(0); } else { VMWAIT(4); }
        SCHED0; SBAR;
#pragma unroll
        for (int i = 0; i < 2; ++i)
#pragma unroll
            for (int kx = 0; kx < 2; ++kx) afB[i][kx] = rdA(rb, 2 + i, kx);
        if (!last) { ST_A(2, kt + 1); ST_A(3, kt + 1); }
        SCHED0;
        __builtin_amdgcn_s_setprio(1);
#pragma unroll
        for (int i = 0; i < 2; ++i)
#pragma unroll
            for (int nf = 0; nf < 4; ++nf) {
                acc[2 + i][nf] = __builtin_amdgcn_mfma_f32_16x16x32_bf16(afB[i][0], bfr[nf][0], acc[2 + i][nf], 0, 0, 0);
                acc[2 + i][nf] = __builtin_amdgcn_mfma_f32_16x16x32_bf16(afB[i][1], bfr[nf][1], acc[2 + i][nf], 0, 0, 0);
            }
        __builtin_amdgcn_s_setprio(0);
    }

#pragma unroll
    for (int m = 0; m < MF; ++m)
#pragma unroll
        for (int j2 = 0; j2 < 4; ++j2) {
            const int r = bm + wm * (MF * 16) + m * 16 + lk * 4 + j2;
#pragma unroll
            for (int n = 0; n < 4; ++n) {
                const int c = n0 + bn + wn * 64 + n * 16 + lrow;
                if (obf) ((bf16*)Cv)[(size_t)r * N + c] = __float2bfloat16(acc[m][n][j2]);
                else     ((float*)Cv)[(size_t)r * N + c] = acc[m][n][j2];
            }
        }
}

// ---- GEMM-2 (256 blocks, BN=128, BK=64, f32 out — unchanged from r17)
__global__ __launch_bounds__(512, 2) void k_gemm2k(const bf16* __restrict__ A,
                                                   const bf16* __restrict__ Bt,
                                                   float* __restrict__ C) {
    extern __shared__ char smem[];
    gemm_body<128>(blockIdx.x, A, Bt, C, TOKENS, HID, VD, 0, 0, 16, smem);
}

// ================================================================ merged front-end
__global__ __launch_bounds__(256) void k_front(const float* __restrict__ hs,
                                               const float* __restrict__ Wq, const float* __restrict__ Wk,
                                               const float* __restrict__ Wv, const float* __restrict__ Wg,
                                               const float* __restrict__ Wo,
                                               const float* __restrict__ Wa, const float* __restrict__ Wb,
                                               bf16* __restrict__ Wt, bf16* __restrict__ Wot,
                                               float* __restrict__ alpha, float* __restrict__ beta,
                                               bf16* __restrict__ hsb) {
    const int bid = blockIdx.x;
    const int tid = threadIdx.x;
    __shared__ float t[32][33];
    __shared__ float red[12][4];

    if (bid < NPREP1) {
        const int tx = tid & 31, ty = tid >> 5;
        const int n0 = (bid % (N1 / 32)) * 32;
        const int k0 = (bid / (N1 / 32)) * 32;
        const float* src; int cb, cs;
        if (n0 < 1536)      { int m = n0;        src = Wq; cb = (m >> 8) * 512 + (m & 255) * 2; cs = 2; }
        else if (n0 < 3072) { int m = n0 - 1536; src = Wk; cb = (m >> 8) * 512 + (m & 255) * 2; cs = 2; }
        else if (n0 < 6144) { int m = n0 - 3072; src = Wv; cb = m; cs = 1; }
        else                { int m = n0 - 6144; src = Wg; cb = m; cs = 1; }
#pragma unroll
        for (int i = 0; i < 4; ++i) {
            int k = k0 + ty + i * 8;
            t[ty + i * 8][tx] = src[(size_t)k * VD + cb + cs * tx];
        }
        __syncthreads();
#pragma unroll
        for (int i = 0; i < 4; ++i) {
            int n = n0 + ty + i * 8;
            Wt[(size_t)n * HID + k0 + tx] = __float2bfloat16(t[tx][ty + i * 8]);
        }
    } else if (bid < NPREP1 + NPREP2) {
        const int b2 = bid - NPREP1;
        const int tx = tid & 31, ty = tid >> 5;
        const int c0 = (b2 % (HID / 32)) * 32;
        const int r0 = (b2 / (HID / 32)) * 32;
#pragma unroll
        for (int i = 0; i < 4; ++i)
            t[ty + i * 8][tx] = Wo[(size_t)(r0 + ty + i * 8) * HID + c0 + tx];
        __syncthreads();
#pragma unroll
        for (int i = 0; i < 4; ++i)
            Wot[(size_t)(c0 + ty + i * 8) * VD + r0 + tx] = __float2bfloat16(t[tx][ty + i * 8]);
    } else {
        const int tok = bid - NPREP1 - NPREP2;
        const float* hrow = hs + (size_t)tok * HID;
        bf16* hbrow = hsb + (size_t)tok * HID;
        const int k0 = tid * 8;
        float4 h1 = *(const float4*)(hrow + k0);
        float4 h2 = *(const float4*)(hrow + k0 + 4);
        float hv[8] = {h1.x, h1.y, h1.z, h1.w, h2.x, h2.y, h2.z, h2.w};
        {
            __hip_bfloat162 pr[4];
#pragma unroll
            for (int i = 0; i < 4; ++i) {
                pr[i].x = __float2bfloat16(hv[2 * i]);
                pr[i].y = __float2bfloat16(hv[2 * i + 1]);
            }
            *(uint4*)(hbrow + k0) = *(const uint4*)pr;
        }
        float part[12];
#pragma unroll
        for (int j = 0; j < 12; ++j) part[j] = 0.f;
#pragma unroll
        for (int i = 0; i < 8; ++i) {
            const int k = k0 + i;
            float2 a0 = *(const float2*)(Wa + (size_t)k * NH);
            float2 a1 = *(const float2*)(Wa + (size_t)k * NH + 2);
            float2 a2 = *(const float2*)(Wa + (size_t)k * NH + 4);
            float2 b0 = *(const float2*)(Wb + (size_t)k * NH);
            float2 b1 = *(const float2*)(Wb + (size_t)k * NH + 2);
            float2 b2 = *(const float2*)(Wb + (size_t)k * NH + 4);
            const float x = hv[i];
            part[0]  = fmaf(x, a0.x, part[0]);  part[1]  = fmaf(x, a0.y, part[1]);
            part[2]  = fmaf(x, a1.x, part[2]);  part[3]  = fmaf(x, a1.y, part[3]);
            part[4]  = fmaf(x, a2.x, part[4]);  part[5]  = fmaf(x, a2.y, part[5]);
            part[6]  = fmaf(x, b0.x, part[6]);  part[7]  = fmaf(x, b0.y, part[7]);
            part[8]  = fmaf(x, b1.x, part[8]);  part[9]  = fmaf(x, b1.y, part[9]);
            part[10] = fmaf(x, b2.x, part[10]); part[11] = fmaf(x, b2.y, part[11]);
        }
        const int lane = tid & 63, wv = tid >> 6;
#pragma unroll
        for (int j = 0; j < 12; ++j) {
            float s = part[j];
            for (int off = 32; off; off >>= 1) s += __shfl_down(s, off);
            if (lane == 0) red[j][wv] = s;
        }
        __syncthreads();
        if (tid < 12) {
            float s = red[tid][0] + red[tid][1] + red[tid][2] + red[tid][3];
            float v = 1.f / (1.f + expf(-s));
            if (tid < 6) alpha[(size_t)tok * NH + tid] = v;
            else         beta [(size_t)tok * NH + tid - 6] = v;
        }
    }
}

// ---------------------------------------------------------------- conv + phase + rotate + local chunk scan (U stored bf16)
__global__ __launch_bounds__(256) void k_scan1(const bf16* __restrict__ X,
                                               const float* __restrict__ alpha,
                                               const float* __restrict__ beta,
                                               const float* __restrict__ cq,
                                               const float* __restrict__ ck,
                                               const float* __restrict__ cv,
                                               bf16* __restrict__ U, float* __restrict__ pp) {
    const int bx = blockIdx.x;
    const int c  = bx % NC;
    const int h  = (bx / NC) % NH;
    const int b  = bx / (NC * NH);
    const int p  = threadIdx.x;
    const int t0 = c * CHUNK;
    const int ch2 = h * HD + 2 * p;
    const float wq0 = cq[ch2 * 4 + 0], wq1 = cq[ch2 * 4 + 1], wq2 = cq[ch2 * 4 + 2], wq3 = cq[ch2 * 4 + 3];
    const float wk0 = ck[ch2 * 4 + 0], wk1 = ck[ch2 * 4 + 1], wk2 = ck[ch2 * 4 + 2], wk3 = ck[ch2 * 4 + 3];
    const float wa0 = cv[ch2 * 4 + 0], wa1 = cv[ch2 * 4 + 1], wa2 = cv[ch2 * 4 + 2], wa3 = cv[ch2 * 4 + 3];
    const float wb0 = cv[(ch2 + 1) * 4 + 0], wb1 = cv[(ch2 + 1) * 4 + 1],
                wb2 = cv[(ch2 + 1) * 4 + 2], wb3 = cv[(ch2 + 1) * 4 + 3];
    const float invf = exp2f(-13.287712379549449f * ((float)p * (1.0f / 256.0f)));
    const int qcol = h * NPAIR + p;
    const int kcol = 1536 + h * NPAIR + p;
    const int vcol = 3072 + ch2;

    float xq[3], xk[3], xv0[3], xv1[3];
#pragma unroll
    for (int i = 0; i < 3; ++i) {
        int t = t0 - 3 + i;
        if (t >= 0) {
            size_t tok = (size_t)b * 2048 + t;
            const bf16* xr = X + tok * N1;
            xq[i] = __bfloat162float(xr[qcol]);
            xk[i] = __bfloat162float(xr[kcol]);
            __hip_bfloat162 vv = *(const __hip_bfloat162*)&xr[vcol];
            xv0[i] = __bfloat162float(vv.x);
            xv1[i] = __bfloat162float(vv.y);
        } else { xq[i] = xk[i] = xv0[i] = xv1[i] = 0.f; }
    }

    float u0 = 0.f, u1 = 0.f, ap = 1.f;
#pragma unroll 4
    for (int t = t0; t < t0 + CHUNK; ++t) {
        const size_t tok = (size_t)b * 2048 + t;
        const bf16* xr = X + tok * N1;
        float nq = __bfloat162float(xr[qcol]);
        float nk = __bfloat162float(xr[kcol]);
        __hip_bfloat162 vv = *(const __hip_bfloat162*)&xr[vcol];
        float nv0 = __bfloat162float(vv.x);
        float nv1 = __bfloat162float(vv.y);
        float yq  = wq3 * nq  + wq2 * xq[2]  + wq1 * xq[1]  + wq0 * xq[0];
        float yk  = wk3 * nk  + wk2 * xk[2]  + wk1 * xk[1]  + wk0 * xk[0];
        float yv0 = wa3 * nv0 + wa2 * xv0[2] + wa1 * xv0[1] + wa0 * xv0[0];
        float yv1 = wb3 * nv1 + wb2 * xv1[2] + wb1 * xv1[1] + wb0 * xv1[0];
        xq[0] = xq[1]; xq[1] = xq[2]; xq[2] = nq;
        xk[0] = xk[1]; xk[1] = xk[2]; xk[2] = nk;
        xv0[0] = xv0[1]; xv0[1] = xv0[2]; xv0[2] = nv0;
        xv1[0] = xv1[1]; xv1[1] = xv1[2]; xv1[2] = nv1;
        float theta = yq * invf, psi = yk * invf;
        float d = psi - theta, sn, cs;
        __sincosf(d, &sn, &cs);
        float w0 = yv0 * cs - yv1 * sn;
        float w1 = yv1 * cs + yv0 * sn;
        float a  = alpha[tok * NH + h];
        float bb = beta [tok * NH + h];
        u0 = fmaf(a, u0, bb * w0);
        u1 = fmaf(a, u1, bb * w1);
        ap *= a;
        __hip_bfloat162 us;
        us.x = __float2bfloat16(u0);
        us.y = __float2bfloat16(u1);
        *(__hip_bfloat162*)&U[tok * (size_t)VD + h * HD + 2 * p] = us;
        if (p == 0) pp[tok * NH + h] = ap;
    }
}

// ---------------------------------------------------------------- cross-chunk carry (batched prefetch, NC=128)
__global__ __launch_bounds__(512) void k_carry(const bf16* __restrict__ U, const float* __restrict__ pp,
                                               float* __restrict__ carry) {
    const int bh = blockIdx.x;
    const int b = bh / NH, h = bh % NH;
    const int d = threadIdx.x;
    float s = 0.f;
    for (int cb = 0; cb < NC; cb += 32) {
        float ue[32], pv[32];
#pragma unroll
        for (int i = 0; i < 32; ++i) {
            size_t tok = (size_t)b * 2048 + (cb + i) * CHUNK + CHUNK - 1;
            ue[i] = __bfloat162float(U[tok * (size_t)VD + h * HD + d]);
            pv[i] = pp[tok * NH + h];
        }
#pragma unroll
        for (int i = 0; i < 32; ++i) {
            carry[((size_t)bh * NC + cb + i) * HD + d] = s;
            s = ue[i] + pv[i] * s;
        }
    }
}

// ---------------------------------------------------------------- carry fix + RMS + SiLU gate -> bf16 O
__global__ __launch_bounds__(256) void k_pass3(const bf16* __restrict__ U, const float* __restrict__ pp,
                                               const float* __restrict__ carry, const bf16* __restrict__ X,
                                               const float* __restrict__ rms_w, bf16* __restrict__ O) {
    const int r    = blockIdx.x * 4 + (threadIdx.x >> 6);
    const int lane = threadIdx.x & 63;
    const size_t tok = r / NH;
    const int h = r % NH;
    const int b = (int)(tok >> 11);
    const int t = (int)(tok & 2047);
    const int c = t / CHUNK;
    const size_t ubase = tok * (size_t)VD + h * HD;
    const size_t cbase = ((size_t)(b * NH + h) * NC + c) * HD;
    const float P = pp[tok * NH + h];

    float u0v[4], u1v[4];
    float s = 0.f;
#pragma unroll
    for (int i = 0; i < 4; ++i) {
        const int pi = lane + i * 64;
        __hip_bfloat162 uu = *(const __hip_bfloat162*)&U[ubase + 2 * pi];
        float2 cy = *(const float2*)&carry[cbase + 2 * pi];
        float u0 = fmaf(P, cy.x, __bfloat162float(uu.x));
        float u1 = fmaf(P, cy.y, __bfloat162float(uu.y));
        u0v[i] = u0; u1v[i] = u1;
        s = fmaf(u0, u0, s);
        s = fmaf(u1, u1, s);
    }
#pragma unroll
    for (int off = 32; off; off >>= 1) s += __shfl_xor(s, off);
    const float rms = rsqrtf(s * (1.f / 512.f) + 1e-5f);

#pragma unroll
    for (int i = 0; i < 4; ++i) {
        const int pi = lane + i * 64;
        __hip_bfloat162 gg = *(const __hip_bfloat162*)&X[tok * N1 + 6144 + h * HD + 2 * pi];
        float g0 = __bfloat162float(gg.x), g1 = __bfloat162float(gg.y);
        float si0 = g0 / (1.f + expf(-g0));
        float si1 = g1 / (1.f + expf(-g1));
        float2 rw = *(const float2*)&rms_w[2 * pi];
        __hip_bfloat162 ob;
        ob.x = __float2bfloat16(u0v[i] * rms * rw.x * si0);
        ob.y = __float2bfloat16(u1v[i] * rms * rw.y * si1);
        *(__hip_bfloat162*)&O[ubase + 2 * pi] = ob;
    }
}

// ----------------------------------------------------------------
extern "C" void kernel_launch(void* const* d_in, const int* in_sizes, int n_in,
                              void* d_out, int out_size, void* d_ws, size_t ws_size,
                              hipStream_t stream) {
    const float* hs   = (const float*)d_in[0];
    const float* Wq   = (const float*)d_in[1];
    const float* Wk   = (const float*)d_in[2];
    const float* Wv   = (const float*)d_in[3];
    const float* Wa   = (const float*)d_in[4];
    const float* Wb   = (const float*)d_in[5];
    const float* Wg   = (const float*)d_in[6];
    const float* Wo   = (const float*)d_in[7];
    const float* cq   = (const float*)d_in[8];
    const float* ck   = (const float*)d_in[9];
    const float* cv   = (const float*)d_in[10];
    const float* rmsw = (const float*)d_in[11];

    char* ws = (char*)d_ws;
    size_t off = 0;
    auto alloc = [&](size_t bytes) -> void* {
        void* p = ws + off;
        off = (off + bytes + 255) & ~(size_t)255;
        return p;
    };
    bf16*  hsb   = (bf16*) alloc((size_t)TOKENS * HID * 2);
    bf16*  Wt    = (bf16*) alloc((size_t)N1 * HID * 2);
    bf16*  Wot   = (bf16*) alloc((size_t)HID * VD * 2);
    bf16*  X     = (bf16*) alloc((size_t)TOKENS * N1 * 2);
    bf16*  U     = (bf16*) alloc((size_t)TOKENS * VD * 2);
    float* alp   = (float*)alloc((size_t)TOKENS * NH * 4);
    float* bet   = (float*)alloc((size_t)TOKENS * NH * 4);
    float* pp    = (float*)alloc((size_t)TOKENS * NH * 4);
    float* carry = (float*)alloc((size_t)2 * NH * NC * HD * 4);
    bf16*  O     = (bf16*)Wt;   // alias: Wt dead after GEMM-1

    hipFuncSetAttribute((const void*)k_gemm1,
                        hipFuncAttributeMaxDynamicSharedMemorySize, 2 * 24576);
    hipFuncSetAttribute((const void*)k_gemm2k,
                        hipFuncAttributeMaxDynamicSharedMemorySize, 2 * 3 * 16384);

    // merged front-end: Wt build + Wo transpose + alpha/beta/hs-cast
    k_front<<<dim3(NPREP1 + NPREP2 + TOKENS), 256, 0, stream>>>(
        hs, Wq, Wk, Wv, Wg, Wo, Wa, Wb, Wt, Wot, alp, bet, hsb);
    // X = hsb @ Wt^T : BK=32, 48 KB LDS -> 2 blocks/CU; 1024 main + 128 tail
    k_gemm1<<<dim3(1152), 512, 2 * 24576, stream>>>(hsb, Wt, X);
    k_scan1<<<2 * NH * NC, 256, 0, stream>>>(X, alp, bet, cq, ck, cv, U, pp);
    k_carry<<<2 * NH, 512, 0, stream>>>(U, pp, carry);
    k_pass3<<<TOKENS * NH / 4, 256, 0, stream>>>(U, pp, carry, X, rmsw, O);
    // out = O @ Wot^T  (M=4096, N=2048, K=3072) -> 256 blocks = exactly 1 round
    k_gemm2k<<<dim3(256), 512, 2 * 3 * 16384, stream>>>(O, Wot, (float*)d_out);
}

// Round 19
// 316.439 us; speedup vs baseline: 1.0725x; 1.0725x over previous
//
#include <hip/hip_runtime.h>
#include <hip/hip_bf16.h>
#include <stdint.h>

using bf16 = __hip_bfloat16;
using mfrag = __attribute__((ext_vector_type(8))) __bf16;   // 8 bf16 = 4 VGPRs
using f32x4 = __attribute__((ext_vector_type(4))) float;

#define TOKENS 4096
#define HID    2048
#define VD     3072
#define NH     6
#define HD     512
#define NPAIR  256
#define N1     9216     /* q_even(1536) | k_even(1536) | v(3072) | g(3072) */
#define NC     128
#define CHUNK  16

#define NPREP1 ((N1 / 32) * (HID / 32))   /* 18432 */
#define NPREP2 ((HID / 32) * (VD / 32))   /*  6144 */

__device__ __forceinline__ void gld_lds16(const bf16* g, bf16* l) {
    __builtin_amdgcn_global_load_lds((const __attribute__((address_space(1))) void*)g,
                                     (__attribute__((address_space(3))) void*)l, 16, 0, 0);
}

#define VMWAIT(n) asm volatile("s_waitcnt vmcnt(" #n ")" ::: "memory")
#define SCHED0    __builtin_amdgcn_sched_barrier(0)
#define SBAR      __builtin_amdgcn_s_barrier()

// ================================================================ FIFO-pipelined 256xBN GEMM body
// BN=256: 4-phase loop (r13 schedule, waits {2,3,4,-}/{2,1,0,-}).
// BN=128: 2-phase loop (16 MFMA per fence; waits {A:2, B:4}, last {2, 0}).
template<int BN_T>
__device__ __forceinline__ void gemm_body(int bid, const bf16* __restrict__ A,
                                          const bf16* __restrict__ Bt,
                                          void* __restrict__ Cv,
                                          int M, int N, int K, int obf,
                                          int n0, int nbn, char* smem) {
    constexpr int WN   = (BN_T == 256) ? 4 : 2;
    constexpr int WM   = 8 / WN;
    constexpr int MF   = (256 / WM) / 16;
    constexpr int AQ   = MF / 4;
    constexpr int SH   = AQ * 16;
    constexpr int NHT  = 2 + BN_T / 128;
    constexpr int HT   = 16384;
    constexpr int SLOT = NHT * HT;

    const int tid  = threadIdx.x;
    const int wave = tid >> 6;
    const int lane = tid & 63;
    const int lrow = lane & 15;
    const int lk   = lane >> 4;
    const int wm   = wave / WN;
    const int wn   = wave % WN;

    const int xcd = bid & 7;
    const int kk2 = bid >> 3;
    const int rn  = nbn >> 1;
    const int jj  = kk2 & 31;
    const int bm  = ((((xcd >> 1) << 2) + (jj & 3)) << 8);
    const int bn  = ((xcd & 1) * rn + (kk2 >> 5) * 8 + (jj >> 2)) * BN_T;

    const int NT = K >> 6;

    auto ST_B = [&](int half, int t) {
        char* sb = smem + (size_t)(t & 1) * SLOT + (2 + half) * HT;
        const int ko = t << 6;
#pragma unroll
        for (int i = 0; i < 2; ++i) {
            const int L = i * 512 + tid;
            const int r = L >> 3;
            const int c = (L & 7) ^ (r & 7);
            gld_lds16(Bt + (size_t)(bn + half * 128 + r) * K + ko + c * 8,
                      (bf16*)(sb + (size_t)L * 16));
        }
    };
    auto ST_A = [&](int unit, int t) {
        char* sb = smem + (size_t)(t & 1) * SLOT;
        const int ko = t << 6;
        const int s  = tid / (SH * 8);
        const int W  = tid % (SH * 8);
        const int rl = W >> 3;
        const int c  = W & 7;
        const int r256 = s * (256 / WM) + unit * SH + rl;
        const int cl = c ^ (r256 & 7);
        const int ht = r256 >> 7, lr = r256 & 127;
        gld_lds16(A + (size_t)(bm + r256) * K + ko + cl * 8,
                  (bf16*)(sb + (size_t)ht * HT + (size_t)lr * 128 + c * 16));
    };

    auto rdA = [&](const char* rb, int mf, int kk) -> mfrag {
        const int r  = wm * (MF * 16) + mf * 16 + lrow;
        const int ht = r >> 7, lr = r & 127;
        const int cc = (kk * 4 + lk) ^ (lr & 7);
        return *(const mfrag*)(rb + (size_t)ht * HT + (size_t)lr * 128 + cc * 16);
    };
    auto rdB = [&](const char* rb, int nf, int kk) -> mfrag {
        const int r  = wn * 64 + nf * 16 + lrow;
        const int ht = r >> 7, lr = r & 127;
        const int cc = (kk * 4 + lk) ^ (lr & 7);
        return *(const mfrag*)(rb + (size_t)(2 + ht) * HT + (size_t)lr * 128 + cc * 16);
    };

    f32x4 acc[MF][4];
#pragma unroll
    for (int m = 0; m < MF; ++m)
#pragma unroll
        for (int n = 0; n < 4; ++n) acc[m][n] = f32x4{0.f, 0.f, 0.f, 0.f};

    // prologue: stage tile 0 in FIFO/consumption order (B0[,B1],A0..A3)
    ST_B(0, 0);
    if (BN_T == 256) ST_B(1, 0);
    ST_A(0, 0); ST_A(1, 0); ST_A(2, 0); ST_A(3, 0);

#define RD_A(AF, band)                                                          \
    _Pragma("unroll")                                                           \
    for (int i = 0; i < AQ; ++i)                                                \
        _Pragma("unroll")                                                       \
        for (int kx = 0; kx < 2; ++kx) AF[i][kx] = rdA(rb, (band) * AQ + i, kx);

#define MFMA_Q(q, AF)                                                           \
    __builtin_amdgcn_s_setprio(1);                                              \
    _Pragma("unroll")                                                           \
    for (int i = 0; i < AQ; ++i)                                                \
        _Pragma("unroll")                                                       \
        for (int nf = 0; nf < 4; ++nf) {                                        \
            const int mi = (q) * AQ + i;                                        \
            acc[mi][nf] = __builtin_amdgcn_mfma_f32_16x16x32_bf16(AF[i][0], bfr[nf][0], acc[mi][nf], 0, 0, 0); \
            acc[mi][nf] = __builtin_amdgcn_mfma_f32_16x16x32_bf16(AF[i][1], bfr[nf][1], acc[mi][nf], 0, 0, 0); \
        }                                                                       \
    __builtin_amdgcn_s_setprio(0);

    if constexpr (BN_T == 128) {
        // ---------------- 2-phase loop: 16 MFMA per fence pair
        for (int kt = 0; kt < NT; ++kt) {
            const char* rb = smem + (size_t)(kt & 1) * SLOT;
            const bool last = (kt == NT - 1);
            mfrag bfr[4][2];
            mfrag afA[2][2], afB[2][2];

            // phase A: wait publishes B0(t),A0(t),A1(t)
            VMWAIT(2);
            SCHED0; SBAR;
#pragma unroll
            for (int nf = 0; nf < 4; ++nf)
#pragma unroll
                for (int kx = 0; kx < 2; ++kx) bfr[nf][kx] = rdB(rb, nf, kx);
#pragma unroll
            for (int i = 0; i < 2; ++i)
#pragma unroll
                for (int kx = 0; kx < 2; ++kx) afA[i][kx] = rdA(rb, i, kx);
            if (!last) { ST_B(0, kt + 1); ST_A(0, kt + 1); ST_A(1, kt + 1); }
            SCHED0;
            __builtin_amdgcn_s_setprio(1);
#pragma unroll
            for (int i = 0; i < 2; ++i)
#pragma unroll
                for (int nf = 0; nf < 4; ++nf) {
                    acc[i][nf] = __builtin_amdgcn_mfma_f32_16x16x32_bf16(afA[i][0], bfr[nf][0], acc[i][nf], 0, 0, 0);
                    acc[i][nf] = __builtin_amdgcn_mfma_f32_16x16x32_bf16(afA[i][1], bfr[nf][1], acc[i][nf], 0, 0, 0);
                }
            __builtin_amdgcn_s_setprio(0);

            // phase B: wait publishes A2(t),A3(t)
            if (last) { VMWAIT(0); } else { VMWAIT(4); }
            SCHED0; SBAR;
#pragma unroll
            for (int i = 0; i < 2; ++i)
#pragma unroll
                for (int kx = 0; kx < 2; ++kx) afB[i][kx] = rdA(rb, 2 + i, kx);
            if (!last) { ST_A(2, kt + 1); ST_A(3, kt + 1); }
            SCHED0;
            __builtin_amdgcn_s_setprio(1);
#pragma unroll
            for (int i = 0; i < 2; ++i)
#pragma unroll
                for (int nf = 0; nf < 4; ++nf) {
                    acc[2 + i][nf] = __builtin_amdgcn_mfma_f32_16x16x32_bf16(afB[i][0], bfr[nf][0], acc[2 + i][nf], 0, 0, 0);
                    acc[2 + i][nf] = __builtin_amdgcn_mfma_f32_16x16x32_bf16(afB[i][1], bfr[nf][1], acc[2 + i][nf], 0, 0, 0);
                }
            __builtin_amdgcn_s_setprio(0);
        }
    } else {
        // ---------------- 4-phase loop (r13 schedule)
        for (int kt = 0; kt < NT; ++kt) {
            const char* rb = smem + (size_t)(kt & 1) * SLOT;
            const bool last = (kt == NT - 1);
            mfrag bfr[4][2];
            mfrag af0[AQ][2], af1[AQ][2], af2[AQ][2], af3[AQ][2];

            // phase 0
            VMWAIT(2);
            SCHED0; SBAR;
#pragma unroll
            for (int nf = 0; nf < 4; ++nf)
#pragma unroll
                for (int kx = 0; kx < 2; ++kx) bfr[nf][kx] = rdB(rb, nf, kx);
            RD_A(af0, 0)
            if (!last) ST_B(0, kt + 1);
            RD_A(af1, 1)
            SCHED0;
            MFMA_Q(0, af0)

            // phase 1
            if (last) { VMWAIT(1); } else { VMWAIT(3); }
            SCHED0; SBAR;
            if (!last) ST_B(1, kt + 1);
            RD_A(af2, 2)
            SCHED0;
            MFMA_Q(1, af1)

            // phase 2
            if (last) { VMWAIT(0); } else { VMWAIT(4); }
            SCHED0; SBAR;
            if (!last) { ST_A(0, kt + 1); ST_A(1, kt + 1); }
            RD_A(af3, 3)
            SCHED0;
            MFMA_Q(2, af2)

            // phase 3
            SBAR;
            if (!last) { ST_A(2, kt + 1); ST_A(3, kt + 1); }
            SCHED0;
            MFMA_Q(3, af3)
        }
    }
#undef RD_A
#undef MFMA_Q

#pragma unroll
    for (int m = 0; m < MF; ++m)
#pragma unroll
        for (int j2 = 0; j2 < 4; ++j2) {
            const int r = bm + wm * (MF * 16) + m * 16 + lk * 4 + j2;
#pragma unroll
            for (int n = 0; n < 4; ++n) {
                const int c = n0 + bn + wn * 64 + n * 16 + lrow;
                if (obf) ((bf16*)Cv)[(size_t)r * N + c] = __float2bfloat16(acc[m][n][j2]);
                else     ((float*)Cv)[(size_t)r * N + c] = acc[m][n][j2];
            }
        }
}

// ---- merged GEMM-1: blocks 0-511 main (BN=256, cols 0-8191), 512-639 tail (BN=128, cols 8192-9215)
__global__ __launch_bounds__(512, 2) void k_gemm1(const bf16* __restrict__ A,
                                                  const bf16* __restrict__ Wt,
                                                  bf16* __restrict__ X) {
    extern __shared__ char smem[];
    if (blockIdx.x < 512)
        gemm_body<256>(blockIdx.x, A, Wt, X, TOKENS, N1, HID, 1, 0, 32, smem);
    else
        gemm_body<128>(blockIdx.x - 512, A, Wt + (size_t)8192 * HID, X, TOKENS, N1, HID, 1, 8192, 8, smem);
}

// ---- GEMM-2 (256 blocks, BN=128, f32 out)
__global__ __launch_bounds__(512, 2) void k_gemm2k(const bf16* __restrict__ A,
                                                   const bf16* __restrict__ Bt,
                                                   float* __restrict__ C) {
    extern __shared__ char smem[];
    gemm_body<128>(blockIdx.x, A, Bt, C, TOKENS, HID, VD, 0, 0, 16, smem);
}

// ================================================================ merged front-end
__global__ __launch_bounds__(256) void k_front(const float* __restrict__ hs,
                                               const float* __restrict__ Wq, const float* __restrict__ Wk,
                                               const float* __restrict__ Wv, const float* __restrict__ Wg,
                                               const float* __restrict__ Wo,
                                               const float* __restrict__ Wa, const float* __restrict__ Wb,
                                               bf16* __restrict__ Wt, bf16* __restrict__ Wot,
                                               float* __restrict__ alpha, float* __restrict__ beta,
                                               bf16* __restrict__ hsb) {
    const int bid = blockIdx.x;
    const int tid = threadIdx.x;
    __shared__ float t[32][33];
    __shared__ float red[12][4];

    if (bid < NPREP1) {
        const int tx = tid & 31, ty = tid >> 5;
        const int n0 = (bid % (N1 / 32)) * 32;
        const int k0 = (bid / (N1 / 32)) * 32;
        const float* src; int cb, cs;
        if (n0 < 1536)      { int m = n0;        src = Wq; cb = (m >> 8) * 512 + (m & 255) * 2; cs = 2; }
        else if (n0 < 3072) { int m = n0 - 1536; src = Wk; cb = (m >> 8) * 512 + (m & 255) * 2; cs = 2; }
        else if (n0 < 6144) { int m = n0 - 3072; src = Wv; cb = m; cs = 1; }
        else                { int m = n0 - 6144; src = Wg; cb = m; cs = 1; }
#pragma unroll
        for (int i = 0; i < 4; ++i) {
            int k = k0 + ty + i * 8;
            t[ty + i * 8][tx] = src[(size_t)k * VD + cb + cs * tx];
        }
        __syncthreads();
#pragma unroll
        for (int i = 0; i < 4; ++i) {
            int n = n0 + ty + i * 8;
            Wt[(size_t)n * HID + k0 + tx] = __float2bfloat16(t[tx][ty + i * 8]);
        }
    } else if (bid < NPREP1 + NPREP2) {
        const int b2 = bid - NPREP1;
        const int tx = tid & 31, ty = tid >> 5;
        const int c0 = (b2 % (HID / 32)) * 32;
        const int r0 = (b2 / (HID / 32)) * 32;
#pragma unroll
        for (int i = 0; i < 4; ++i)
            t[ty + i * 8][tx] = Wo[(size_t)(r0 + ty + i * 8) * HID + c0 + tx];
        __syncthreads();
#pragma unroll
        for (int i = 0; i < 4; ++i)
            Wot[(size_t)(c0 + ty + i * 8) * VD + r0 + tx] = __float2bfloat16(t[tx][ty + i * 8]);
    } else {
        const int tok = bid - NPREP1 - NPREP2;
        const float* hrow = hs + (size_t)tok * HID;
        bf16* hbrow = hsb + (size_t)tok * HID;
        const int k0 = tid * 8;
        float4 h1 = *(const float4*)(hrow + k0);
        float4 h2 = *(const float4*)(hrow + k0 + 4);
        float hv[8] = {h1.x, h1.y, h1.z, h1.w, h2.x, h2.y, h2.z, h2.w};
        {
            __hip_bfloat162 pr[4];
#pragma unroll
            for (int i = 0; i < 4; ++i) {
                pr[i].x = __float2bfloat16(hv[2 * i]);
                pr[i].y = __float2bfloat16(hv[2 * i + 1]);
            }
            *(uint4*)(hbrow + k0) = *(const uint4*)pr;
        }
        float part[12];
#pragma unroll
        for (int j = 0; j < 12; ++j) part[j] = 0.f;
#pragma unroll
        for (int i = 0; i < 8; ++i) {
            const int k = k0 + i;
            float2 a0 = *(const float2*)(Wa + (size_t)k * NH);
            float2 a1 = *(const float2*)(Wa + (size_t)k * NH + 2);
            float2 a2 = *(const float2*)(Wa + (size_t)k * NH + 4);
            float2 b0 = *(const float2*)(Wb + (size_t)k * NH);
            float2 b1 = *(const float2*)(Wb + (size_t)k * NH + 2);
            float2 b2 = *(const float2*)(Wb + (size_t)k * NH + 4);
            const float x = hv[i];
            part[0]  = fmaf(x, a0.x, part[0]);  part[1]  = fmaf(x, a0.y, part[1]);
            part[2]  = fmaf(x, a1.x, part[2]);  part[3]  = fmaf(x, a1.y, part[3]);
            part[4]  = fmaf(x, a2.x, part[4]);  part[5]  = fmaf(x, a2.y, part[5]);
            part[6]  = fmaf(x, b0.x, part[6]);  part[7]  = fmaf(x, b0.y, part[7]);
            part[8]  = fmaf(x, b1.x, part[8]);  part[9]  = fmaf(x, b1.y, part[9]);
            part[10] = fmaf(x, b2.x, part[10]); part[11] = fmaf(x, b2.y, part[11]);
        }
        const int lane = tid & 63, wv = tid >> 6;
#pragma unroll
        for (int j = 0; j < 12; ++j) {
            float s = part[j];
            for (int off = 32; off; off >>= 1) s += __shfl_down(s, off);
            if (lane == 0) red[j][wv] = s;
        }
        __syncthreads();
        if (tid < 12) {
            float s = red[tid][0] + red[tid][1] + red[tid][2] + red[tid][3];
            float v = 1.f / (1.f + expf(-s));
            if (tid < 6) alpha[(size_t)tok * NH + tid] = v;
            else         beta [(size_t)tok * NH + tid - 6] = v;
        }
    }
}

// ---------------------------------------------------------------- conv + phase + rotate + local chunk scan (U stored bf16)
__global__ __launch_bounds__(256) void k_scan1(const bf16* __restrict__ X,
                                               const float* __restrict__ alpha,
                                               const float* __restrict__ beta,
                                               const float* __restrict__ cq,
                                               const float* __restrict__ ck,
                                               const float* __restrict__ cv,
                                               bf16* __restrict__ U, float* __restrict__ pp) {
    const int bx = blockIdx.x;
    const int c  = bx % NC;
    const int h  = (bx / NC) % NH;
    const int b  = bx / (NC * NH);
    const int p  = threadIdx.x;
    const int t0 = c * CHUNK;
    const int ch2 = h * HD + 2 * p;
    const float wq0 = cq[ch2 * 4 + 0], wq1 = cq[ch2 * 4 + 1], wq2 = cq[ch2 * 4 + 2], wq3 = cq[ch2 * 4 + 3];
    const float wk0 = ck[ch2 * 4 + 0], wk1 = ck[ch2 * 4 + 1], wk2 = ck[ch2 * 4 + 2], wk3 = ck[ch2 * 4 + 3];
    const float wa0 = cv[ch2 * 4 + 0], wa1 = cv[ch2 * 4 + 1], wa2 = cv[ch2 * 4 + 2], wa3 = cv[ch2 * 4 + 3];
    const float wb0 = cv[(ch2 + 1) * 4 + 0], wb1 = cv[(ch2 + 1) * 4 + 1],
                wb2 = cv[(ch2 + 1) * 4 + 2], wb3 = cv[(ch2 + 1) * 4 + 3];
    const float invf = exp2f(-13.287712379549449f * ((float)p * (1.0f / 256.0f)));
    const int qcol = h * NPAIR + p;
    const int kcol = 1536 + h * NPAIR + p;
    const int vcol = 3072 + ch2;

    float xq[3], xk[3], xv0[3], xv1[3];
#pragma unroll
    for (int i = 0; i < 3; ++i) {
        int t = t0 - 3 + i;
        if (t >= 0) {
            size_t tok = (size_t)b * 2048 + t;
            const bf16* xr = X + tok * N1;
            xq[i] = __bfloat162float(xr[qcol]);
            xk[i] = __bfloat162float(xr[kcol]);
            __hip_bfloat162 vv = *(const __hip_bfloat162*)&xr[vcol];
            xv0[i] = __bfloat162float(vv.x);
            xv1[i] = __bfloat162float(vv.y);
        } else { xq[i] = xk[i] = xv0[i] = xv1[i] = 0.f; }
    }

    float u0 = 0.f, u1 = 0.f, ap = 1.f;
#pragma unroll 4
    for (int t = t0; t < t0 + CHUNK; ++t) {
        const size_t tok = (size_t)b * 2048 + t;
        const bf16* xr = X + tok * N1;
        float nq = __bfloat162float(xr[qcol]);
        float nk = __bfloat162float(xr[kcol]);
        __hip_bfloat162 vv = *(const __hip_bfloat162*)&xr[vcol];
        float nv0 = __bfloat162float(vv.x);
        float nv1 = __bfloat162float(vv.y);
        float yq  = wq3 * nq  + wq2 * xq[2]  + wq1 * xq[1]  + wq0 * xq[0];
        float yk  = wk3 * nk  + wk2 * xk[2]  + wk1 * xk[1]  + wk0 * xk[0];
        float yv0 = wa3 * nv0 + wa2 * xv0[2] + wa1 * xv0[1] + wa0 * xv0[0];
        float yv1 = wb3 * nv1 + wb2 * xv1[2] + wb1 * xv1[1] + wb0 * xv1[0];
        xq[0] = xq[1]; xq[1] = xq[2]; xq[2] = nq;
        xk[0] = xk[1]; xk[1] = xk[2]; xk[2] = nk;
        xv0[0] = xv0[1]; xv0[1] = xv0[2]; xv0[2] = nv0;
        xv1[0] = xv1[1]; xv1[1] = xv1[2]; xv1[2] = nv1;
        float theta = yq * invf, psi = yk * invf;
        float d = psi - theta, sn, cs;
        __sincosf(d, &sn, &cs);
        float w0 = yv0 * cs - yv1 * sn;
        float w1 = yv1 * cs + yv0 * sn;
        float a  = alpha[tok * NH + h];
        float bb = beta [tok * NH + h];
        u0 = fmaf(a, u0, bb * w0);
        u1 = fmaf(a, u1, bb * w1);
        ap *= a;
        __hip_bfloat162 us;
        us.x = __float2bfloat16(u0);
        us.y = __float2bfloat16(u1);
        *(__hip_bfloat162*)&U[tok * (size_t)VD + h * HD + 2 * p] = us;
        if (p == 0) pp[tok * NH + h] = ap;
    }
}

// ---------------------------------------------------------------- cross-chunk carry (batched prefetch, NC=128)
__global__ __launch_bounds__(512) void k_carry(const bf16* __restrict__ U, const float* __restrict__ pp,
                                               float* __restrict__ carry) {
    const int bh = blockIdx.x;
    const int b = bh / NH, h = bh % NH;
    const int d = threadIdx.x;
    float s = 0.f;
    for (int cb = 0; cb < NC; cb += 32) {
        float ue[32], pv[32];
#pragma unroll
        for (int i = 0; i < 32; ++i) {
            size_t tok = (size_t)b * 2048 + (cb + i) * CHUNK + CHUNK - 1;
            ue[i] = __bfloat162float(U[tok * (size_t)VD + h * HD + d]);
            pv[i] = pp[tok * NH + h];
        }
#pragma unroll
        for (int i = 0; i < 32; ++i) {
            carry[((size_t)bh * NC + cb + i) * HD + d] = s;
            s = ue[i] + pv[i] * s;
        }
    }
}

// ---------------------------------------------------------------- carry fix + RMS + SiLU gate -> bf16 O
__global__ __launch_bounds__(256) void k_pass3(const bf16* __restrict__ U, const float* __restrict__ pp,
                                               const float* __restrict__ carry, const bf16* __restrict__ X,
                                               const float* __restrict__ rms_w, bf16* __restrict__ O) {
    const int r    = blockIdx.x * 4 + (threadIdx.x >> 6);
    const int lane = threadIdx.x & 63;
    const size_t tok = r / NH;
    const int h = r % NH;
    const int b = (int)(tok >> 11);
    const int t = (int)(tok & 2047);
    const int c = t / CHUNK;
    const size_t ubase = tok * (size_t)VD + h * HD;
    const size_t cbase = ((size_t)(b * NH + h) * NC + c) * HD;
    const float P = pp[tok * NH + h];

    float u0v[4], u1v[4];
    float s = 0.f;
#pragma unroll
    for (int i = 0; i < 4; ++i) {
        const int pi = lane + i * 64;
        __hip_bfloat162 uu = *(const __hip_bfloat162*)&U[ubase + 2 * pi];
        float2 cy = *(const float2*)&carry[cbase + 2 * pi];
        float u0 = fmaf(P, cy.x, __bfloat162float(uu.x));
        float u1 = fmaf(P, cy.y, __bfloat162float(uu.y));
        u0v[i] = u0; u1v[i] = u1;
        s = fmaf(u0, u0, s);
        s = fmaf(u1, u1, s);
    }
#pragma unroll
    for (int off = 32; off; off >>= 1) s += __shfl_xor(s, off);
    const float rms = rsqrtf(s * (1.f / 512.f) + 1e-5f);

#pragma unroll
    for (int i = 0; i < 4; ++i) {
        const int pi = lane + i * 64;
        __hip_bfloat162 gg = *(const __hip_bfloat162*)&X[tok * N1 + 6144 + h * HD + 2 * pi];
        float g0 = __bfloat162float(gg.x), g1 = __bfloat162float(gg.y);
        float si0 = g0 / (1.f + expf(-g0));
        float si1 = g1 / (1.f + expf(-g1));
        float2 rw = *(const float2*)&rms_w[2 * pi];
        __hip_bfloat162 ob;
        ob.x = __float2bfloat16(u0v[i] * rms * rw.x * si0);
        ob.y = __float2bfloat16(u1v[i] * rms * rw.y * si1);
        *(__hip_bfloat162*)&O[ubase + 2 * pi] = ob;
    }
}

// ----------------------------------------------------------------
extern "C" void kernel_launch(void* const* d_in, const int* in_sizes, int n_in,
                              void* d_out, int out_size, void* d_ws, size_t ws_size,
                              hipStream_t stream) {
    const float* hs   = (const float*)d_in[0];
    const float* Wq   = (const float*)d_in[1];
    const float* Wk   = (const float*)d_in[2];
    const float* Wv   = (const float*)d_in[3];
    const float* Wa   = (const float*)d_in[4];
    const float* Wb   = (const float*)d_in[5];
    const float* Wg   = (const float*)d_in[6];
    const float* Wo   = (const float*)d_in[7];
    const float* cq   = (const float*)d_in[8];
    const float* ck   = (const float*)d_in[9];
    const float* cv   = (const float*)d_in[10];
    const float* rmsw = (const float*)d_in[11];

    char* ws = (char*)d_ws;
    size_t off = 0;
    auto alloc = [&](size_t bytes) -> void* {
        void* p = ws + off;
        off = (off + bytes + 255) & ~(size_t)255;
        return p;
    };
    bf16*  hsb   = (bf16*) alloc((size_t)TOKENS * HID * 2);
    bf16*  Wt    = (bf16*) alloc((size_t)N1 * HID * 2);
    bf16*  Wot   = (bf16*) alloc((size_t)HID * VD * 2);
    bf16*  X     = (bf16*) alloc((size_t)TOKENS * N1 * 2);
    bf16*  U     = (bf16*) alloc((size_t)TOKENS * VD * 2);
    float* alp   = (float*)alloc((size_t)TOKENS * NH * 4);
    float* bet   = (float*)alloc((size_t)TOKENS * NH * 4);
    float* pp    = (float*)alloc((size_t)TOKENS * NH * 4);
    float* carry = (float*)alloc((size_t)2 * NH * NC * HD * 4);
    bf16*  O     = (bf16*)Wt;   // alias: Wt dead after GEMM-1

    hipFuncSetAttribute((const void*)k_gemm1,
                        hipFuncAttributeMaxDynamicSharedMemorySize, 2 * 4 * 16384);
    hipFuncSetAttribute((const void*)k_gemm2k,
                        hipFuncAttributeMaxDynamicSharedMemorySize, 2 * 3 * 16384);

    // merged front-end: Wt build + Wo transpose + alpha/beta/hs-cast
    k_front<<<dim3(NPREP1 + NPREP2 + TOKENS), 256, 0, stream>>>(
        hs, Wq, Wk, Wv, Wg, Wo, Wa, Wb, Wt, Wot, alp, bet, hsb);
    // X = hsb @ Wt^T : merged main(512 blocks, BN=256) + tail(128 blocks, BN=128)
    k_gemm1<<<dim3(640), 512, 2 * 4 * 16384, stream>>>(hsb, Wt, X);
    k_scan1<<<2 * NH * NC, 256, 0, stream>>>(X, alp, bet, cq, ck, cv, U, pp);
    k_carry<<<2 * NH, 512, 0, stream>>>(U, pp, carry);
    k_pass3<<<TOKENS * NH / 4, 256, 0, stream>>>(U, pp, carry, X, rmsw, O);
    // out = O @ Wot^T  (M=4096, N=2048, K=3072) -> 256 blocks = exactly 1 round
    k_gemm2k<<<dim3(256), 512, 2 * 3 * 16384, stream>>>(O, Wot, (float*)d_out);
}

// Round 20
// 312.667 us; speedup vs baseline: 1.0855x; 1.0121x over previous
//
#include <hip/hip_runtime.h>
#include <hip/hip_bf16.h>
#include <stdint.h>

using bf16 = __hip_bfloat16;
using mfrag = __attribute__((ext_vector_type(8))) __bf16;   // 8 bf16 = 4 VGPRs
using f32x4 = __attribute__((ext_vector_type(4))) float;

#define TOKENS 4096
#define HID    2048
#define VD     3072
#define NH     6
#define HD     512
#define NPAIR  256
#define N1     9216     /* q_even(1536) | k_even(1536) | v(3072) | g(3072) */
#define NC     128
#define CHUNK  16

#define NPREP1 ((N1 / 32) * (HID / 32))   /* 18432 */
#define NPREP2 ((HID / 32) * (VD / 32))   /*  6144 */

__device__ __forceinline__ void gld_lds16(const bf16* g, bf16* l) {
    __builtin_amdgcn_global_load_lds((const __attribute__((address_space(1))) void*)g,
                                     (__attribute__((address_space(3))) void*)l, 16, 0, 0);
}

#define VMWAIT(n) asm volatile("s_waitcnt vmcnt(" #n ")" ::: "memory")
#define SCHED0    __builtin_amdgcn_sched_barrier(0)
#define SBAR      __builtin_amdgcn_s_barrier()

// ================================================================ FIFO-pipelined 256xBN GEMM body
// BN=256: 4-phase loop (r13 schedule, waits {2,3,4,-}/{2,1,0,-}).
// BN=128: 2-phase loop (16 MFMA per fence; waits {A:2, B:4}, last {2, 0}).
template<int BN_T>
__device__ __forceinline__ void gemm_body(int bid, const bf16* __restrict__ A,
                                          const bf16* __restrict__ Bt,
                                          void* __restrict__ Cv,
                                          int M, int N, int K, int obf,
                                          int n0, int nbn, char* smem) {
    constexpr int WN   = (BN_T == 256) ? 4 : 2;
    constexpr int WM   = 8 / WN;
    constexpr int MF   = (256 / WM) / 16;
    constexpr int AQ   = MF / 4;
    constexpr int SH   = AQ * 16;
    constexpr int NHT  = 2 + BN_T / 128;
    constexpr int HT   = 16384;
    constexpr int SLOT = NHT * HT;

    const int tid  = threadIdx.x;
    const int wave = tid >> 6;
    const int lane = tid & 63;
    const int lrow = lane & 15;
    const int lk   = lane >> 4;
    const int wm   = wave / WN;
    const int wn   = wave % WN;

    const int xcd = bid & 7;
    const int kk2 = bid >> 3;
    const int rn  = nbn >> 1;
    const int jj  = kk2 & 31;
    const int bm  = ((((xcd >> 1) << 2) + (jj & 3)) << 8);
    const int bn  = ((xcd & 1) * rn + (kk2 >> 5) * 8 + (jj >> 2)) * BN_T;

    const int NT = K >> 6;

    auto ST_B = [&](int half, int t) {
        char* sb = smem + (size_t)(t & 1) * SLOT + (2 + half) * HT;
        const int ko = t << 6;
#pragma unroll
        for (int i = 0; i < 2; ++i) {
            const int L = i * 512 + tid;
            const int r = L >> 3;
            const int c = (L & 7) ^ (r & 7);
            gld_lds16(Bt + (size_t)(bn + half * 128 + r) * K + ko + c * 8,
                      (bf16*)(sb + (size_t)L * 16));
        }
    };
    auto ST_A = [&](int unit, int t) {
        char* sb = smem + (size_t)(t & 1) * SLOT;
        const int ko = t << 6;
        const int s  = tid / (SH * 8);
        const int W  = tid % (SH * 8);
        const int rl = W >> 3;
        const int c  = W & 7;
        const int r256 = s * (256 / WM) + unit * SH + rl;
        const int cl = c ^ (r256 & 7);
        const int ht = r256 >> 7, lr = r256 & 127;
        gld_lds16(A + (size_t)(bm + r256) * K + ko + cl * 8,
                  (bf16*)(sb + (size_t)ht * HT + (size_t)lr * 128 + c * 16));
    };

    auto rdA = [&](const char* rb, int mf, int kk) -> mfrag {
        const int r  = wm * (MF * 16) + mf * 16 + lrow;
        const int ht = r >> 7, lr = r & 127;
        const int cc = (kk * 4 + lk) ^ (lr & 7);
        return *(const mfrag*)(rb + (size_t)ht * HT + (size_t)lr * 128 + cc * 16);
    };
    auto rdB = [&](const char* rb, int nf, int kk) -> mfrag {
        const int r  = wn * 64 + nf * 16 + lrow;
        const int ht = r >> 7, lr = r & 127;
        const int cc = (kk * 4 + lk) ^ (lr & 7);
        return *(const mfrag*)(rb + (size_t)(2 + ht) * HT + (size_t)lr * 128 + cc * 16);
    };

    f32x4 acc[MF][4];
#pragma unroll
    for (int m = 0; m < MF; ++m)
#pragma unroll
        for (int n = 0; n < 4; ++n) acc[m][n] = f32x4{0.f, 0.f, 0.f, 0.f};

    // prologue: stage tile 0 in FIFO/consumption order (B0[,B1],A0..A3)
    ST_B(0, 0);
    if (BN_T == 256) ST_B(1, 0);
    ST_A(0, 0); ST_A(1, 0); ST_A(2, 0); ST_A(3, 0);

#define RD_A(AF, band)                                                          \
    _Pragma("unroll")                                                           \
    for (int i = 0; i < AQ; ++i)                                                \
        _Pragma("unroll")                                                       \
        for (int kx = 0; kx < 2; ++kx) AF[i][kx] = rdA(rb, (band) * AQ + i, kx);

#define MFMA_Q(q, AF)                                                           \
    __builtin_amdgcn_s_setprio(1);                                              \
    _Pragma("unroll")                                                           \
    for (int i = 0; i < AQ; ++i)                                                \
        _Pragma("unroll")                                                       \
        for (int nf = 0; nf < 4; ++nf) {                                        \
            const int mi = (q) * AQ + i;                                        \
            acc[mi][nf] = __builtin_amdgcn_mfma_f32_16x16x32_bf16(AF[i][0], bfr[nf][0], acc[mi][nf], 0, 0, 0); \
            acc[mi][nf] = __builtin_amdgcn_mfma_f32_16x16x32_bf16(AF[i][1], bfr[nf][1], acc[mi][nf], 0, 0, 0); \
        }                                                                       \
    __builtin_amdgcn_s_setprio(0);

    if constexpr (BN_T == 128) {
        // ---------------- 2-phase loop: 16 MFMA per fence pair
        for (int kt = 0; kt < NT; ++kt) {
            const char* rb = smem + (size_t)(kt & 1) * SLOT;
            const bool last = (kt == NT - 1);
            mfrag bfr[4][2];
            mfrag afA[2][2], afB[2][2];

            // phase A: wait publishes B0(t),A0(t),A1(t)
            VMWAIT(2);
            SCHED0; SBAR;
#pragma unroll
            for (int nf = 0; nf < 4; ++nf)
#pragma unroll
                for (int kx = 0; kx < 2; ++kx) bfr[nf][kx] = rdB(rb, nf, kx);
#pragma unroll
            for (int i = 0; i < 2; ++i)
#pragma unroll
                for (int kx = 0; kx < 2; ++kx) afA[i][kx] = rdA(rb, i, kx);
            if (!last) { ST_B(0, kt + 1); ST_A(0, kt + 1); ST_A(1, kt + 1); }
            SCHED0;
            __builtin_amdgcn_s_setprio(1);
#pragma unroll
            for (int i = 0; i < 2; ++i)
#pragma unroll
                for (int nf = 0; nf < 4; ++nf) {
                    acc[i][nf] = __builtin_amdgcn_mfma_f32_16x16x32_bf16(afA[i][0], bfr[nf][0], acc[i][nf], 0, 0, 0);
                    acc[i][nf] = __builtin_amdgcn_mfma_f32_16x16x32_bf16(afA[i][1], bfr[nf][1], acc[i][nf], 0, 0, 0);
                }
            __builtin_amdgcn_s_setprio(0);

            // phase B: wait publishes A2(t),A3(t)
            if (last) { VMWAIT(0); } else { VMWAIT(4); }
            SCHED0; SBAR;
#pragma unroll
            for (int i = 0; i < 2; ++i)
#pragma unroll
                for (int kx = 0; kx < 2; ++kx) afB[i][kx] = rdA(rb, 2 + i, kx);
            if (!last) { ST_A(2, kt + 1); ST_A(3, kt + 1); }
            SCHED0;
            __builtin_amdgcn_s_setprio(1);
#pragma unroll
            for (int i = 0; i < 2; ++i)
#pragma unroll
                for (int nf = 0; nf < 4; ++nf) {
                    acc[2 + i][nf] = __builtin_amdgcn_mfma_f32_16x16x32_bf16(afB[i][0], bfr[nf][0], acc[2 + i][nf], 0, 0, 0);
                    acc[2 + i][nf] = __builtin_amdgcn_mfma_f32_16x16x32_bf16(afB[i][1], bfr[nf][1], acc[2 + i][nf], 0, 0, 0);
                }
            __builtin_amdgcn_s_setprio(0);
        }
    } else {
        // ---------------- 4-phase loop (r13 schedule)
        for (int kt = 0; kt < NT; ++kt) {
            const char* rb = smem + (size_t)(kt & 1) * SLOT;
            const bool last = (kt == NT - 1);
            mfrag bfr[4][2];
            mfrag af0[AQ][2], af1[AQ][2], af2[AQ][2], af3[AQ][2];

            // phase 0
            VMWAIT(2);
            SCHED0; SBAR;
#pragma unroll
            for (int nf = 0; nf < 4; ++nf)
#pragma unroll
                for (int kx = 0; kx < 2; ++kx) bfr[nf][kx] = rdB(rb, nf, kx);
            RD_A(af0, 0)
            if (!last) ST_B(0, kt + 1);
            RD_A(af1, 1)
            SCHED0;
            MFMA_Q(0, af0)

            // phase 1
            if (last) { VMWAIT(1); } else { VMWAIT(3); }
            SCHED0; SBAR;
            if (!last) ST_B(1, kt + 1);
            RD_A(af2, 2)
            SCHED0;
            MFMA_Q(1, af1)

            // phase 2
            if (last) { VMWAIT(0); } else { VMWAIT(4); }
            SCHED0; SBAR;
            if (!last) { ST_A(0, kt + 1); ST_A(1, kt + 1); }
            RD_A(af3, 3)
            SCHED0;
            MFMA_Q(2, af2)

            // phase 3
            SBAR;
            if (!last) { ST_A(2, kt + 1); ST_A(3, kt + 1); }
            SCHED0;
            MFMA_Q(3, af3)
        }
    }
#undef RD_A
#undef MFMA_Q

#pragma unroll
    for (int m = 0; m < MF; ++m)
#pragma unroll
        for (int j2 = 0; j2 < 4; ++j2) {
            const int r = bm + wm * (MF * 16) + m * 16 + lk * 4 + j2;
#pragma unroll
            for (int n = 0; n < 4; ++n) {
                const int c = n0 + bn + wn * 64 + n * 16 + lrow;
                if (obf) ((bf16*)Cv)[(size_t)r * N + c] = __float2bfloat16(acc[m][n][j2]);
                else     ((float*)Cv)[(size_t)r * N + c] = acc[m][n][j2];
            }
        }
}

// ---- merged GEMM-1, TAIL-FIRST dispatch order:
// blocks 0-127: tail (BN=128, cols 8192-9215) -- short blocks issue first so the
// final round packs with main work instead of straggling; blocks 128-639: main (BN=256).
__global__ __launch_bounds__(512, 2) void k_gemm1(const bf16* __restrict__ A,
                                                  const bf16* __restrict__ Wt,
                                                  bf16* __restrict__ X) {
    extern __shared__ char smem[];
    if (blockIdx.x < 128)
        gemm_body<128>(blockIdx.x, A, Wt + (size_t)8192 * HID, X, TOKENS, N1, HID, 1, 8192, 8, smem);
    else
        gemm_body<256>(blockIdx.x - 128, A, Wt, X, TOKENS, N1, HID, 1, 0, 32, smem);
}

// ---- GEMM-2 (256 blocks, BN=128, f32 out)
__global__ __launch_bounds__(512, 2) void k_gemm2k(const bf16* __restrict__ A,
                                                   const bf16* __restrict__ Bt,
                                                   float* __restrict__ C) {
    extern __shared__ char smem[];
    gemm_body<128>(blockIdx.x, A, Bt, C, TOKENS, HID, VD, 0, 0, 16, smem);
}

// ================================================================ merged front-end
__global__ __launch_bounds__(256) void k_front(const float* __restrict__ hs,
                                               const float* __restrict__ Wq, const float* __restrict__ Wk,
                                               const float* __restrict__ Wv, const float* __restrict__ Wg,
                                               const float* __restrict__ Wo,
                                               const float* __restrict__ Wa, const float* __restrict__ Wb,
                                               bf16* __restrict__ Wt, bf16* __restrict__ Wot,
                                               float* __restrict__ alpha, float* __restrict__ beta,
                                               bf16* __restrict__ hsb) {
    const int bid = blockIdx.x;
    const int tid = threadIdx.x;
    __shared__ float t[32][33];
    __shared__ float red[12][4];

    if (bid < NPREP1) {
        const int tx = tid & 31, ty = tid >> 5;
        const int n0 = (bid % (N1 / 32)) * 32;
        const int k0 = (bid / (N1 / 32)) * 32;
        const float* src; int cb, cs;
        if (n0 < 1536)      { int m = n0;        src = Wq; cb = (m >> 8) * 512 + (m & 255) * 2; cs = 2; }
        else if (n0 < 3072) { int m = n0 - 1536; src = Wk; cb = (m >> 8) * 512 + (m & 255) * 2; cs = 2; }
        else if (n0 < 6144) { int m = n0 - 3072; src = Wv; cb = m; cs = 1; }
        else                { int m = n0 - 6144; src = Wg; cb = m; cs = 1; }
#pragma unroll
        for (int i = 0; i < 4; ++i) {
            int k = k0 + ty + i * 8;
            t[ty + i * 8][tx] = src[(size_t)k * VD + cb + cs * tx];
        }
        __syncthreads();
#pragma unroll
        for (int i = 0; i < 4; ++i) {
            int n = n0 + ty + i * 8;
            Wt[(size_t)n * HID + k0 + tx] = __float2bfloat16(t[tx][ty + i * 8]);
        }
    } else if (bid < NPREP1 + NPREP2) {
        const int b2 = bid - NPREP1;
        const int tx = tid & 31, ty = tid >> 5;
        const int c0 = (b2 % (HID / 32)) * 32;
        const int r0 = (b2 / (HID / 32)) * 32;
#pragma unroll
        for (int i = 0; i < 4; ++i)
            t[ty + i * 8][tx] = Wo[(size_t)(r0 + ty + i * 8) * HID + c0 + tx];
        __syncthreads();
#pragma unroll
        for (int i = 0; i < 4; ++i)
            Wot[(size_t)(c0 + ty + i * 8) * VD + r0 + tx] = __float2bfloat16(t[tx][ty + i * 8]);
    } else {
        const int tok = bid - NPREP1 - NPREP2;
        const float* hrow = hs + (size_t)tok * HID;
        bf16* hbrow = hsb + (size_t)tok * HID;
        const int k0 = tid * 8;
        float4 h1 = *(const float4*)(hrow + k0);
        float4 h2 = *(const float4*)(hrow + k0 + 4);
        float hv[8] = {h1.x, h1.y, h1.z, h1.w, h2.x, h2.y, h2.z, h2.w};
        {
            __hip_bfloat162 pr[4];
#pragma unroll
            for (int i = 0; i < 4; ++i) {
                pr[i].x = __float2bfloat16(hv[2 * i]);
                pr[i].y = __float2bfloat16(hv[2 * i + 1]);
            }
            *(uint4*)(hbrow + k0) = *(const uint4*)pr;
        }
        float part[12];
#pragma unroll
        for (int j = 0; j < 12; ++j) part[j] = 0.f;
#pragma unroll
        for (int i = 0; i < 8; ++i) {
            const int k = k0 + i;
            float2 a0 = *(const float2*)(Wa + (size_t)k * NH);
            float2 a1 = *(const float2*)(Wa + (size_t)k * NH + 2);
            float2 a2 = *(const float2*)(Wa + (size_t)k * NH + 4);
            float2 b0 = *(const float2*)(Wb + (size_t)k * NH);
            float2 b1 = *(const float2*)(Wb + (size_t)k * NH + 2);
            float2 b2 = *(const float2*)(Wb + (size_t)k * NH + 4);
            const float x = hv[i];
            part[0]  = fmaf(x, a0.x, part[0]);  part[1]  = fmaf(x, a0.y, part[1]);
            part[2]  = fmaf(x, a1.x, part[2]);  part[3]  = fmaf(x, a1.y, part[3]);
            part[4]  = fmaf(x, a2.x, part[4]);  part[5]  = fmaf(x, a2.y, part[5]);
            part[6]  = fmaf(x, b0.x, part[6]);  part[7]  = fmaf(x, b0.y, part[7]);
            part[8]  = fmaf(x, b1.x, part[8]);  part[9]  = fmaf(x, b1.y, part[9]);
            part[10] = fmaf(x, b2.x, part[10]); part[11] = fmaf(x, b2.y, part[11]);
        }
        const int lane = tid & 63, wv = tid >> 6;
#pragma unroll
        for (int j = 0; j < 12; ++j) {
            float s = part[j];
            for (int off = 32; off; off >>= 1) s += __shfl_down(s, off);
            if (lane == 0) red[j][wv] = s;
        }
        __syncthreads();
        if (tid < 12) {
            float s = red[tid][0] + red[tid][1] + red[tid][2] + red[tid][3];
            float v = 1.f / (1.f + expf(-s));
            if (tid < 6) alpha[(size_t)tok * NH + tid] = v;
            else         beta [(size_t)tok * NH + tid - 6] = v;
        }
    }
}

// ---------------------------------------------------------------- conv + phase + rotate + local chunk scan (U stored bf16)
__global__ __launch_bounds__(256) void k_scan1(const bf16* __restrict__ X,
                                               const float* __restrict__ alpha,
                                               const float* __restrict__ beta,
                                               const float* __restrict__ cq,
                                               const float* __restrict__ ck,
                                               const float* __restrict__ cv,
                                               bf16* __restrict__ U, float* __restrict__ pp) {
    const int bx = blockIdx.x;
    const int c  = bx % NC;
    const int h  = (bx / NC) % NH;
    const int b  = bx / (NC * NH);
    const int p  = threadIdx.x;
    const int t0 = c * CHUNK;
    const int ch2 = h * HD + 2 * p;
    const float wq0 = cq[ch2 * 4 + 0], wq1 = cq[ch2 * 4 + 1], wq2 = cq[ch2 * 4 + 2], wq3 = cq[ch2 * 4 + 3];
    const float wk0 = ck[ch2 * 4 + 0], wk1 = ck[ch2 * 4 + 1], wk2 = ck[ch2 * 4 + 2], wk3 = ck[ch2 * 4 + 3];
    const float wa0 = cv[ch2 * 4 + 0], wa1 = cv[ch2 * 4 + 1], wa2 = cv[ch2 * 4 + 2], wa3 = cv[ch2 * 4 + 3];
    const float wb0 = cv[(ch2 + 1) * 4 + 0], wb1 = cv[(ch2 + 1) * 4 + 1],
                wb2 = cv[(ch2 + 1) * 4 + 2], wb3 = cv[(ch2 + 1) * 4 + 3];
    const float invf = exp2f(-13.287712379549449f * ((float)p * (1.0f / 256.0f)));
    const int qcol = h * NPAIR + p;
    const int kcol = 1536 + h * NPAIR + p;
    const int vcol = 3072 + ch2;

    float xq[3], xk[3], xv0[3], xv1[3];
#pragma unroll
    for (int i = 0; i < 3; ++i) {
        int t = t0 - 3 + i;
        if (t >= 0) {
            size_t tok = (size_t)b * 2048 + t;
            const bf16* xr = X + tok * N1;
            xq[i] = __bfloat162float(xr[qcol]);
            xk[i] = __bfloat162float(xr[kcol]);
            __hip_bfloat162 vv = *(const __hip_bfloat162*)&xr[vcol];
            xv0[i] = __bfloat162float(vv.x);
            xv1[i] = __bfloat162float(vv.y);
        } else { xq[i] = xk[i] = xv0[i] = xv1[i] = 0.f; }
    }

    float u0 = 0.f, u1 = 0.f, ap = 1.f;
#pragma unroll 4
    for (int t = t0; t < t0 + CHUNK; ++t) {
        const size_t tok = (size_t)b * 2048 + t;
        const bf16* xr = X + tok * N1;
        float nq = __bfloat162float(xr[qcol]);
        float nk = __bfloat162float(xr[kcol]);
        __hip_bfloat162 vv = *(const __hip_bfloat162*)&xr[vcol];
        float nv0 = __bfloat162float(vv.x);
        float nv1 = __bfloat162float(vv.y);
        float yq  = wq3 * nq  + wq2 * xq[2]  + wq1 * xq[1]  + wq0 * xq[0];
        float yk  = wk3 * nk  + wk2 * xk[2]  + wk1 * xk[1]  + wk0 * xk[0];
        float yv0 = wa3 * nv0 + wa2 * xv0[2] + wa1 * xv0[1] + wa0 * xv0[0];
        float yv1 = wb3 * nv1 + wb2 * xv1[2] + wb1 * xv1[1] + wb0 * xv1[0];
        xq[0] = xq[1]; xq[1] = xq[2]; xq[2] = nq;
        xk[0] = xk[1]; xk[1] = xk[2]; xk[2] = nk;
        xv0[0] = xv0[1]; xv0[1] = xv0[2]; xv0[2] = nv0;
        xv1[0] = xv1[1]; xv1[1] = xv1[2]; xv1[2] = nv1;
        float theta = yq * invf, psi = yk * invf;
        float d = psi - theta, sn, cs;
        __sincosf(d, &sn, &cs);
        float w0 = yv0 * cs - yv1 * sn;
        float w1 = yv1 * cs + yv0 * sn;
        float a  = alpha[tok * NH + h];
        float bb = beta [tok * NH + h];
        u0 = fmaf(a, u0, bb * w0);
        u1 = fmaf(a, u1, bb * w1);
        ap *= a;
        __hip_bfloat162 us;
        us.x = __float2bfloat16(u0);
        us.y = __float2bfloat16(u1);
        *(__hip_bfloat162*)&U[tok * (size_t)VD + h * HD + 2 * p] = us;
        if (p == 0) pp[tok * NH + h] = ap;
    }
}

// ---------------------------------------------------------------- cross-chunk carry (batched prefetch, NC=128)
__global__ __launch_bounds__(512) void k_carry(const bf16* __restrict__ U, const float* __restrict__ pp,
                                               float* __restrict__ carry) {
    const int bh = blockIdx.x;
    const int b = bh / NH, h = bh % NH;
    const int d = threadIdx.x;
    float s = 0.f;
    for (int cb = 0; cb < NC; cb += 32) {
        float ue[32], pv[32];
#pragma unroll
        for (int i = 0; i < 32; ++i) {
            size_t tok = (size_t)b * 2048 + (cb + i) * CHUNK + CHUNK - 1;
            ue[i] = __bfloat162float(U[tok * (size_t)VD + h * HD + d]);
            pv[i] = pp[tok * NH + h];
        }
#pragma unroll
        for (int i = 0; i < 32; ++i) {
            carry[((size_t)bh * NC + cb + i) * HD + d] = s;
            s = ue[i] + pv[i] * s;
        }
    }
}

// ---------------------------------------------------------------- carry fix + RMS + SiLU gate -> bf16 O
__global__ __launch_bounds__(256) void k_pass3(const bf16* __restrict__ U, const float* __restrict__ pp,
                                               const float* __restrict__ carry, const bf16* __restrict__ X,
                                               const float* __restrict__ rms_w, bf16* __restrict__ O) {
    const int r    = blockIdx.x * 4 + (threadIdx.x >> 6);
    const int lane = threadIdx.x & 63;
    const size_t tok = r / NH;
    const int h = r % NH;
    const int b = (int)(tok >> 11);
    const int t = (int)(tok & 2047);
    const int c = t / CHUNK;
    const size_t ubase = tok * (size_t)VD + h * HD;
    const size_t cbase = ((size_t)(b * NH + h) * NC + c) * HD;
    const float P = pp[tok * NH + h];

    float u0v[4], u1v[4];
    float s = 0.f;
#pragma unroll
    for (int i = 0; i < 4; ++i) {
        const int pi = lane + i * 64;
        __hip_bfloat162 uu = *(const __hip_bfloat162*)&U[ubase + 2 * pi];
        float2 cy = *(const float2*)&carry[cbase + 2 * pi];
        float u0 = fmaf(P, cy.x, __bfloat162float(uu.x));
        float u1 = fmaf(P, cy.y, __bfloat162float(uu.y));
        u0v[i] = u0; u1v[i] = u1;
        s = fmaf(u0, u0, s);
        s = fmaf(u1, u1, s);
    }
#pragma unroll
    for (int off = 32; off; off >>= 1) s += __shfl_xor(s, off);
    const float rms = rsqrtf(s * (1.f / 512.f) + 1e-5f);

#pragma unroll
    for (int i = 0; i < 4; ++i) {
        const int pi = lane + i * 64;
        __hip_bfloat162 gg = *(const __hip_bfloat162*)&X[tok * N1 + 6144 + h * HD + 2 * pi];
        float g0 = __bfloat162float(gg.x), g1 = __bfloat162float(gg.y);
        float si0 = g0 / (1.f + expf(-g0));
        float si1 = g1 / (1.f + expf(-g1));
        float2 rw = *(const float2*)&rms_w[2 * pi];
        __hip_bfloat162 ob;
        ob.x = __float2bfloat16(u0v[i] * rms * rw.x * si0);
        ob.y = __float2bfloat16(u1v[i] * rms * rw.y * si1);
        *(__hip_bfloat162*)&O[ubase + 2 * pi] = ob;
    }
}

// ----------------------------------------------------------------
extern "C" void kernel_launch(void* const* d_in, const int* in_sizes, int n_in,
                              void* d_out, int out_size, void* d_ws, size_t ws_size,
                              hipStream_t stream) {
    const float* hs   = (const float*)d_in[0];
    const float* Wq   = (const float*)d_in[1];
    const float* Wk   = (const float*)d_in[2];
    const float* Wv   = (const float*)d_in[3];
    const float* Wa   = (const float*)d_in[4];
    const float* Wb   = (const float*)d_in[5];
    const float* Wg   = (const float*)d_in[6];
    const float* Wo   = (const float*)d_in[7];
    const float* cq   = (const float*)d_in[8];
    const float* ck   = (const float*)d_in[9];
    const float* cv   = (const float*)d_in[10];
    const float* rmsw = (const float*)d_in[11];

    char* ws = (char*)d_ws;
    size_t off = 0;
    auto alloc = [&](size_t bytes) -> void* {
        void* p = ws + off;
        off = (off + bytes + 255) & ~(size_t)255;
        return p;
    };
    bf16*  hsb   = (bf16*) alloc((size_t)TOKENS * HID * 2);
    bf16*  Wt    = (bf16*) alloc((size_t)N1 * HID * 2);
    bf16*  Wot   = (bf16*) alloc((size_t)HID * VD * 2);
    bf16*  X     = (bf16*) alloc((size_t)TOKENS * N1 * 2);
    bf16*  U     = (bf16*) alloc((size_t)TOKENS * VD * 2);
    float* alp   = (float*)alloc((size_t)TOKENS * NH * 4);
    float* bet   = (float*)alloc((size_t)TOKENS * NH * 4);
    float* pp    = (float*)alloc((size_t)TOKENS * NH * 4);
    float* carry = (float*)alloc((size_t)2 * NH * NC * HD * 4);
    bf16*  O     = (bf16*)Wt;   // alias: Wt dead after GEMM-1

    hipFuncSetAttribute((const void*)k_gemm1,
                        hipFuncAttributeMaxDynamicSharedMemorySize, 2 * 4 * 16384);
    hipFuncSetAttribute((const void*)k_gemm2k,
                        hipFuncAttributeMaxDynamicSharedMemorySize, 2 * 3 * 16384);

    // merged front-end: Wt build + Wo transpose + alpha/beta/hs-cast
    k_front<<<dim3(NPREP1 + NPREP2 + TOKENS), 256, 0, stream>>>(
        hs, Wq, Wk, Wv, Wg, Wo, Wa, Wb, Wt, Wot, alp, bet, hsb);
    // X = hsb @ Wt^T : tail-first(128 blocks, BN=128) + main(512 blocks, BN=256)
    k_gemm1<<<dim3(640), 512, 2 * 4 * 16384, stream>>>(hsb, Wt, X);
    k_scan1<<<2 * NH * NC, 256, 0, stream>>>(X, alp, bet, cq, ck, cv, U, pp);
    k_carry<<<2 * NH, 512, 0, stream>>>(U, pp, carry);
    k_pass3<<<TOKENS * NH / 4, 256, 0, stream>>>(U, pp, carry, X, rmsw, O);
    // out = O @ Wot^T  (M=4096, N=2048, K=3072) -> 256 blocks = exactly 1 round
    k_gemm2k<<<dim3(256), 512, 2 * 3 * 16384, stream>>>(O, Wot, (float*)d_out);
}